// Round 1
// baseline (3031.944 us; speedup 1.0000x reference)
//
#include <hip/hip_runtime.h>

#define N_ 100
#define G_ 100
#define E_ 128
#define D_ 16
#define PAD 132   // LDS row stride in floats: 528 B = 16B-aligned rows, conflict-free lane-per-row

__device__ __forceinline__ float fc(float4 v, int i) {
    union { float4 v4; float f[4]; } u; u.v4 = v; return u.f[i];
}

extern "C" __global__ void __launch_bounds__(256, 1)
pomo_decoder(const float* __restrict__ nodes,   // [B,N,E]
             const float* __restrict__ last,    // [B,G,E]
             const float* __restrict__ mask,    // [B,G,N]
             const float* __restrict__ Wqg,     // [E,128]
             const float* __restrict__ Wqf,
             const float* __restrict__ Wql,
             const float* __restrict__ Wk,
             const float* __restrict__ Wv,
             const float* __restrict__ Wc,
             const float* __restrict__ bc,      // [128]
             float* __restrict__ out)           // [B,G,N]
{
    __shared__ float s_q[N_ * PAD];   // q -> out_concat (attention output)
    __shared__ float s_k[N_ * PAD];   // k -> mh_atten_out
    __shared__ float s_v[N_ * PAD];   // v -> probs staging (first 100*101 floats)
    __shared__ float s_graph[E_];
    __shared__ float s_qg[E_];
    __shared__ float s_red[256];

    const int b   = blockIdx.x;
    const int tid = threadIdx.x;
    const int j   = tid & 127;   // column / n-index for GEMM-ish phases
    const int r2  = tid >> 7;    // 0/1: row-group

    const float* nb = nodes + (size_t)b * N_ * E_;
    const float* lb = last  + (size_t)b * G_ * E_;
    const float* mb = mask  + (size_t)b * G_ * N_;
    float*       ob = out   + (size_t)b * G_ * N_;

    // ---------------- A0: graph = mean over N of nodes ----------------
    {
        float ssum = 0.f;
        const int n0 = r2 * 50;
        for (int n = n0; n < n0 + 50; ++n) ssum += nb[n * E_ + j];
        s_red[tid] = ssum;
    }
    __syncthreads();
    if (tid < E_) s_graph[tid] = (s_red[tid] + s_red[tid + 128]) * (1.0f / (float)N_);
    __syncthreads();

    // ---------------- A1: q_graph = graph @ Wq_graph ----------------
    if (tid < E_) {
        float acc = 0.f;
        for (int e = 0; e < E_; ++e) acc += s_graph[e] * Wqg[e * E_ + j];
        s_qg[j] = acc;
    }
    __syncthreads();

    // ---------------- A2: q = last @ (Wqf + Wql) + q_graph  -> s_q ----------------
    for (int chunk = 0; chunk < 13; ++chunk) {
        const int rbase = chunk * 8 + r2 * 4;
        const int p0 = min(rbase + 0, G_ - 1);
        const int p1 = min(rbase + 1, G_ - 1);
        const int p2 = min(rbase + 2, G_ - 1);
        const int p3 = min(rbase + 3, G_ - 1);
        float acc0 = 0.f, acc1 = 0.f, acc2 = 0.f, acc3 = 0.f;
        for (int e0 = 0; e0 < E_; e0 += 4) {
            const float4 a0 = *(const float4*)&lb[p0 * E_ + e0];
            const float4 a1 = *(const float4*)&lb[p1 * E_ + e0];
            const float4 a2 = *(const float4*)&lb[p2 * E_ + e0];
            const float4 a3 = *(const float4*)&lb[p3 * E_ + e0];
            #pragma unroll
            for (int ee = 0; ee < 4; ++ee) {
                const float w = Wqf[(e0 + ee) * E_ + j] + Wql[(e0 + ee) * E_ + j];
                acc0 += fc(a0, ee) * w;
                acc1 += fc(a1, ee) * w;
                acc2 += fc(a2, ee) * w;
                acc3 += fc(a3, ee) * w;
            }
        }
        const float qg = s_qg[j];
        if (rbase + 0 < G_) s_q[(rbase + 0) * PAD + j] = acc0 + qg;
        if (rbase + 1 < G_) s_q[(rbase + 1) * PAD + j] = acc1 + qg;
        if (rbase + 2 < G_) s_q[(rbase + 2) * PAD + j] = acc2 + qg;
        if (rbase + 3 < G_) s_q[(rbase + 3) * PAD + j] = acc3 + qg;
    }

    // ---------------- A3: k = nodes@Wk, v = nodes@Wv  -> s_k, s_v ----------------
    for (int chunk = 0; chunk < 13; ++chunk) {
        const int rbase = chunk * 8 + r2 * 4;
        const int p0 = min(rbase + 0, N_ - 1);
        const int p1 = min(rbase + 1, N_ - 1);
        const int p2 = min(rbase + 2, N_ - 1);
        const int p3 = min(rbase + 3, N_ - 1);
        float k0a = 0.f, k1a = 0.f, k2a = 0.f, k3a = 0.f;
        float v0a = 0.f, v1a = 0.f, v2a = 0.f, v3a = 0.f;
        for (int e0 = 0; e0 < E_; e0 += 4) {
            const float4 a0 = *(const float4*)&nb[p0 * E_ + e0];
            const float4 a1 = *(const float4*)&nb[p1 * E_ + e0];
            const float4 a2 = *(const float4*)&nb[p2 * E_ + e0];
            const float4 a3 = *(const float4*)&nb[p3 * E_ + e0];
            #pragma unroll
            for (int ee = 0; ee < 4; ++ee) {
                const float wk = Wk[(e0 + ee) * E_ + j];
                const float wv = Wv[(e0 + ee) * E_ + j];
                const float x0 = fc(a0, ee), x1 = fc(a1, ee), x2 = fc(a2, ee), x3 = fc(a3, ee);
                k0a += x0 * wk; k1a += x1 * wk; k2a += x2 * wk; k3a += x3 * wk;
                v0a += x0 * wv; v1a += x1 * wv; v2a += x2 * wv; v3a += x3 * wv;
            }
        }
        if (rbase + 0 < N_) { s_k[(rbase + 0) * PAD + j] = k0a; s_v[(rbase + 0) * PAD + j] = v0a; }
        if (rbase + 1 < N_) { s_k[(rbase + 1) * PAD + j] = k1a; s_v[(rbase + 1) * PAD + j] = v1a; }
        if (rbase + 2 < N_) { s_k[(rbase + 2) * PAD + j] = k2a; s_v[(rbase + 2) * PAD + j] = v2a; }
        if (rbase + 3 < N_) { s_k[(rbase + 3) * PAD + j] = k3a; s_v[(rbase + 3) * PAD + j] = v3a; }
    }
    __syncthreads();

    // ---------------- B: 8-head masked attention, online softmax ----------------
    // thread (g = tid&127, hh = tid>>7) handles heads {0+hh,2+hh,...} for row g.
    // Writes its out slice over its own q slice (same slot) -> no barriers in loop.
    const int g  = j;
    const int hh = r2;
    if (g < G_) {
        #pragma unroll
        for (int hi = 0; hi < 4; ++hi) {
            const int c = (hi * 2 + hh) * D_;
            float* qrow = &s_q[g * PAD + c];
            const float4 q0 = *(const float4*)&qrow[0];
            const float4 q1 = *(const float4*)&qrow[4];
            const float4 q2 = *(const float4*)&qrow[8];
            const float4 q3 = *(const float4*)&qrow[12];
            float m = -1e30f, l = 0.f;
            float4 A0 = {0,0,0,0}, A1 = {0,0,0,0}, A2 = {0,0,0,0}, A3 = {0,0,0,0};
            for (int n = 0; n < N_; ++n) {
                const float* krow = &s_k[n * PAD + c];
                const float4 k0 = *(const float4*)&krow[0];
                const float4 k1 = *(const float4*)&krow[4];
                const float4 k2 = *(const float4*)&krow[8];
                const float4 k3 = *(const float4*)&krow[12];
                float s0 = q0.x*k0.x + q0.y*k0.y + q0.z*k0.z + q0.w*k0.w;
                float s1 = q1.x*k1.x + q1.y*k1.y + q1.z*k1.z + q1.w*k1.w;
                float s2 = q2.x*k2.x + q2.y*k2.y + q2.z*k2.z + q2.w*k2.w;
                float s3 = q3.x*k3.x + q3.y*k3.y + q3.z*k3.z + q3.w*k3.w;
                const float s = ((s0 + s1) + (s2 + s3)) * 0.25f + mb[g * N_ + n];
                const float* vrow = &s_v[n * PAD + c];
                const float4 v0 = *(const float4*)&vrow[0];
                const float4 v1 = *(const float4*)&vrow[4];
                const float4 v2 = *(const float4*)&vrow[8];
                const float4 v3 = *(const float4*)&vrow[12];
                if (s > m) {            // new max: rescale (rare after warm-up)
                    const float corr = __expf(m - s);
                    m = s;
                    l = l * corr + 1.f; // p = 1
                    A0.x = A0.x*corr + v0.x; A0.y = A0.y*corr + v0.y; A0.z = A0.z*corr + v0.z; A0.w = A0.w*corr + v0.w;
                    A1.x = A1.x*corr + v1.x; A1.y = A1.y*corr + v1.y; A1.z = A1.z*corr + v1.z; A1.w = A1.w*corr + v1.w;
                    A2.x = A2.x*corr + v2.x; A2.y = A2.y*corr + v2.y; A2.z = A2.z*corr + v2.z; A2.w = A2.w*corr + v2.w;
                    A3.x = A3.x*corr + v3.x; A3.y = A3.y*corr + v3.y; A3.z = A3.z*corr + v3.z; A3.w = A3.w*corr + v3.w;
                } else {
                    const float p = __expf(s - m);
                    l += p;
                    A0.x += p*v0.x; A0.y += p*v0.y; A0.z += p*v0.z; A0.w += p*v0.w;
                    A1.x += p*v1.x; A1.y += p*v1.y; A1.z += p*v1.z; A1.w += p*v1.w;
                    A2.x += p*v2.x; A2.y += p*v2.y; A2.z += p*v2.z; A2.w += p*v2.w;
                    A3.x += p*v3.x; A3.y += p*v3.y; A3.z += p*v3.z; A3.w += p*v3.w;
                }
            }
            const float inv = 1.f / l;
            *(float4*)&qrow[0]  = make_float4(A0.x*inv, A0.y*inv, A0.z*inv, A0.w*inv);
            *(float4*)&qrow[4]  = make_float4(A1.x*inv, A1.y*inv, A1.z*inv, A1.w*inv);
            *(float4*)&qrow[8]  = make_float4(A2.x*inv, A2.y*inv, A2.z*inv, A2.w*inv);
            *(float4*)&qrow[12] = make_float4(A3.x*inv, A3.y*inv, A3.z*inv, A3.w*inv);
        }
    }
    __syncthreads();

    // ---------------- C0: mh = out_concat @ W_comb + b_comb  -> s_k ----------------
    for (int chunk = 0; chunk < 13; ++chunk) {
        const int rbase = chunk * 8 + r2 * 4;
        const int p0 = min(rbase + 0, G_ - 1);
        const int p1 = min(rbase + 1, G_ - 1);
        const int p2 = min(rbase + 2, G_ - 1);
        const int p3 = min(rbase + 3, G_ - 1);
        float acc0 = 0.f, acc1 = 0.f, acc2 = 0.f, acc3 = 0.f;
        for (int e0 = 0; e0 < E_; e0 += 4) {
            const float4 a0 = *(const float4*)&s_q[p0 * PAD + e0];
            const float4 a1 = *(const float4*)&s_q[p1 * PAD + e0];
            const float4 a2 = *(const float4*)&s_q[p2 * PAD + e0];
            const float4 a3 = *(const float4*)&s_q[p3 * PAD + e0];
            #pragma unroll
            for (int ee = 0; ee < 4; ++ee) {
                const float w = Wc[(e0 + ee) * E_ + j];
                acc0 += fc(a0, ee) * w;
                acc1 += fc(a1, ee) * w;
                acc2 += fc(a2, ee) * w;
                acc3 += fc(a3, ee) * w;
            }
        }
        const float bj = bc[j];
        if (rbase + 0 < G_) s_k[(rbase + 0) * PAD + j] = acc0 + bj;
        if (rbase + 1 < G_) s_k[(rbase + 1) * PAD + j] = acc1 + bj;
        if (rbase + 2 < G_) s_k[(rbase + 2) * PAD + j] = acc2 + bj;
        if (rbase + 3 < G_) s_k[(rbase + 3) * PAD + j] = acc3 + bj;
    }
    __syncthreads();

    // ---------------- C1: pointer scores + tanh clip + softmax -> s_v staging ----------------
    // thread (g, hh): n in [hh*50, hh*50+50). tanh clip bounds score at +-10 -> fixed-shift softmax.
    if (g < G_) {
        float4 mh[32];
        #pragma unroll
        for (int e4 = 0; e4 < 32; ++e4) mh[e4] = *(const float4*)&s_k[g * PAD + e4 * 4];
        const int n0 = hh * 50;
        float lpart = 0.f;
        for (int n = n0; n < n0 + 50; ++n) {
            const float4* nr = (const float4*)&nb[n * E_];
            float a0 = 0.f, a1 = 0.f, a2 = 0.f, a3 = 0.f;
            #pragma unroll
            for (int e4 = 0; e4 < 32; e4 += 4) {
                const float4 x0 = nr[e4 + 0];
                const float4 x1 = nr[e4 + 1];
                const float4 x2 = nr[e4 + 2];
                const float4 x3 = nr[e4 + 3];
                a0 += mh[e4+0].x*x0.x + mh[e4+0].y*x0.y + mh[e4+0].z*x0.z + mh[e4+0].w*x0.w;
                a1 += mh[e4+1].x*x1.x + mh[e4+1].y*x1.y + mh[e4+1].z*x1.z + mh[e4+1].w*x1.w;
                a2 += mh[e4+2].x*x2.x + mh[e4+2].y*x2.y + mh[e4+2].z*x2.z + mh[e4+2].w*x2.w;
                a3 += mh[e4+3].x*x3.x + mh[e4+3].y*x3.y + mh[e4+3].z*x3.z + mh[e4+3].w*x3.w;
            }
            const float sc2 = ((a0 + a1) + (a2 + a3)) * 0.08838834764831845f; // 1/sqrt(128)
            const float scl = 10.f * tanhf(sc2) + mb[g * N_ + n];
            const float pe  = __expf(scl - 10.f);   // clipped score <= 10 -> stable
            lpart += pe;
            s_v[g * 101 + n] = pe;
        }
        s_red[tid] = lpart;
    }
    __syncthreads();
    if (g < G_) {
        const float inv = 1.f / (s_red[g] + s_red[g + 128]);
        const int n0 = hh * 50;
        for (int n = n0; n < n0 + 50; ++n) s_v[g * 101 + n] *= inv;
    }
    __syncthreads();

    // ---------------- coalesced store of probs ----------------
    for (int idx = tid; idx < G_ * N_; idx += 256) {
        const int gg = idx / N_;
        const int nn = idx - gg * N_;
        ob[idx] = s_v[gg * 101 + nn];
    }
}

extern "C" void kernel_launch(void* const* d_in, const int* in_sizes, int n_in,
                              void* d_out, int out_size, void* d_ws, size_t ws_size,
                              hipStream_t stream) {
    const float* nodes = (const float*)d_in[0];
    const float* last  = (const float*)d_in[1];
    const float* mask  = (const float*)d_in[2];
    const float* Wqg   = (const float*)d_in[3];
    const float* Wqf   = (const float*)d_in[4];
    const float* Wql   = (const float*)d_in[5];
    const float* Wk    = (const float*)d_in[6];
    const float* Wv    = (const float*)d_in[7];
    const float* Wc    = (const float*)d_in[8];
    const float* bc    = (const float*)d_in[9];
    float* out = (float*)d_out;

    const int B = in_sizes[0] / (N_ * E_);   // 2048
    hipLaunchKernelGGL(pomo_decoder, dim3(B), dim3(256), 0, stream,
                       nodes, last, mask, Wqg, Wqf, Wql, Wk, Wv, Wc, bc, out);
}

// Round 2
// 2753.760 us; speedup vs baseline: 1.1010x; 1.1010x over previous
//
#include <hip/hip_runtime.h>
#include <math.h>

#define N_ 100
#define G_ 100
#define E_ 128
#define D_ 16

#define SK 132   // k/v stride: 528B rows, 16B-aligned for b128 tile loads
#define SO 129   // q / o / mh stride: odd -> conflict-free lane-per-row b32
#define SM 101   // mask / probs stride: odd -> conflict-free

__device__ __forceinline__ float rlane(float v, int lane) {
    return __uint_as_float(__builtin_amdgcn_readlane(__float_as_uint(v), lane));
}
__device__ __forceinline__ float fc(float4 v, int i) {
    union { float4 v4; float f[4]; } u; u.v4 = v; return u.f[i];
}

extern "C" __global__ void __launch_bounds__(1024, 4)
pomo_decoder(const float* __restrict__ nodes,   // [B,N,E]
             const float* __restrict__ last,    // [B,G,E]
             const float* __restrict__ mask,    // [B,G,N]
             const float* __restrict__ Wqg,
             const float* __restrict__ Wqf,
             const float* __restrict__ Wql,
             const float* __restrict__ Wk,
             const float* __restrict__ Wv,
             const float* __restrict__ Wc,
             const float* __restrict__ bc,
             float* __restrict__ out)           // [B,G,N]
{
    // 3*13200 + 1024 + 256 = 40880 floats = 163520 B  (<= 163840)
    __shared__ float S[3 * 13200 + 1024 + 256];
    float* R1    = S;            // k (SK)  -> mh (SO)
    float* R2    = S + 13200;    // v (SK)  -> o (SO) -> probs (SM)
    float* R3    = S + 26400;    // q (SO)  -> mask (SM)
    float* RED   = S + 39600;    // [1024]
    float* GRAPH = S + 40624;    // [128]
    float* QG    = S + 40752;    // [128]

    const int tid  = threadIdx.x;
    const int j    = tid & 127;          // column / g index
    const int r8   = tid >> 7;           // 0..7
    const int lane = tid & 63;
    const int b    = blockIdx.x;

    const float* nb = nodes + (size_t)b * N_ * E_;
    const float* lb = last  + (size_t)b * G_ * E_;
    const float* mb = mask  + (size_t)b * G_ * N_;
    float*       ob = out   + (size_t)b * G_ * N_;

    // ---------------- A0: graph = mean over N ----------------
    {
        float ssum = 0.f;
        #pragma unroll
        for (int c = 0; c < 13; ++c) {
            int p = r8 + 8 * c;
            if (p < N_) ssum += nb[p * E_ + j];
        }
        RED[tid] = ssum;
    }
    __syncthreads();
    if (tid < E_) {
        float s = 0.f;
        #pragma unroll
        for (int r = 0; r < 8; ++r) s += RED[r * 128 + tid];
        GRAPH[tid] = s * (1.f / (float)N_);
    }
    __syncthreads();
    // ---------------- A1: q_graph = graph @ Wq_graph ----------------
    if (tid < E_) {
        float acc = 0.f;
        for (int e = 0; e < E_; ++e) acc = fmaf(GRAPH[e], Wqg[e * E_ + tid], acc);
        QG[tid] = acc;
    }
    __syncthreads();

    // ---------------- A2: q = last @ (Wqf+Wql) + qg  -> R3 (stride SO) ----------------
    {
        float acc[13];
        #pragma unroll
        for (int c = 0; c < 13; ++c) acc[c] = 0.f;
        for (int e0 = 0; e0 < E_; e0 += 4) {
            float w[4];
            #pragma unroll
            for (int ee = 0; ee < 4; ++ee)
                w[ee] = Wqf[(e0 + ee) * E_ + j] + Wql[(e0 + ee) * E_ + j];
            #pragma unroll
            for (int c = 0; c < 13; ++c) {
                const int p = min(r8 + 8 * c, G_ - 1);
                float4 a = *(const float4*)&lb[p * E_ + e0];
                acc[c] = fmaf(fc(a,0), w[0], acc[c]);
                acc[c] = fmaf(fc(a,1), w[1], acc[c]);
                acc[c] = fmaf(fc(a,2), w[2], acc[c]);
                acc[c] = fmaf(fc(a,3), w[3], acc[c]);
            }
        }
        const float qg = QG[j];
        #pragma unroll
        for (int c = 0; c < 13; ++c) {
            int p = r8 + 8 * c;
            if (p < G_) R3[p * SO + j] = acc[c] + qg;
        }
    }

    // ---------------- A3: k = nodes@Wk -> R1, v = nodes@Wv -> R2 (stride SK) ----------------
    {
        float ak[13], av[13];
        #pragma unroll
        for (int c = 0; c < 13; ++c) { ak[c] = 0.f; av[c] = 0.f; }
        for (int e0 = 0; e0 < E_; e0 += 4) {
            float wk[4], wv[4];
            #pragma unroll
            for (int ee = 0; ee < 4; ++ee) {
                wk[ee] = Wk[(e0 + ee) * E_ + j];
                wv[ee] = Wv[(e0 + ee) * E_ + j];
            }
            #pragma unroll
            for (int c = 0; c < 13; ++c) {
                const int p = min(r8 + 8 * c, N_ - 1);
                float4 a = *(const float4*)&nb[p * E_ + e0];
                ak[c] = fmaf(fc(a,0), wk[0], ak[c]);
                ak[c] = fmaf(fc(a,1), wk[1], ak[c]);
                ak[c] = fmaf(fc(a,2), wk[2], ak[c]);
                ak[c] = fmaf(fc(a,3), wk[3], ak[c]);
                av[c] = fmaf(fc(a,0), wv[0], av[c]);
                av[c] = fmaf(fc(a,1), wv[1], av[c]);
                av[c] = fmaf(fc(a,2), wv[2], av[c]);
                av[c] = fmaf(fc(a,3), wv[3], av[c]);
            }
        }
        #pragma unroll
        for (int c = 0; c < 13; ++c) {
            int p = r8 + 8 * c;
            if (p < N_) { R1[p * SK + j] = ak[c]; R2[p * SK + j] = av[c]; }
        }
    }
    __syncthreads();   // q,k,v ready

    // ---------------- B: attention. thread (g=j, h=r8); k/v lane-distributed + readlane ----
    const int g  = j;
    const int gg = min(g, G_ - 1);
    const int h  = r8;
    const int c  = h * D_;

    float q[16];
    #pragma unroll
    for (int i4 = 0; i4 < 4; ++i4) {
        // q stored stride SO (odd): scalar reads, conflict-free
        q[i4*4+0] = R3[gg * SO + c + i4*4+0];
        q[i4*4+1] = R3[gg * SO + c + i4*4+1];
        q[i4*4+2] = R3[gg * SO + c + i4*4+2];
        q[i4*4+3] = R3[gg * SO + c + i4*4+3];
    }
    float kr[16], vr[16];
    {
        const int row = lane;            // rows 0..63
        #pragma unroll
        for (int i4 = 0; i4 < 4; ++i4) {
            float4 kk = *(const float4*)&R1[row * SK + c + i4*4];
            float4 vv = *(const float4*)&R2[row * SK + c + i4*4];
            kr[i4*4+0]=kk.x; kr[i4*4+1]=kk.y; kr[i4*4+2]=kk.z; kr[i4*4+3]=kk.w;
            vr[i4*4+0]=vv.x; vr[i4*4+1]=vv.y; vr[i4*4+2]=vv.z; vr[i4*4+3]=vv.w;
        }
    }
    __syncthreads();   // all q reads done; R3 can be reused

    // stage mask -> R3 (stride SM), coalesced global read
    for (int idx = tid; idx < G_ * N_; idx += 1024) {
        int gr = idx / N_;
        int nn = idx - gr * N_;
        R3[gr * SM + nn] = mb[idx];
    }
    __syncthreads();

    float m = -INFINITY, l = 0.f;
    float A[16];
    #pragma unroll
    for (int i = 0; i < 16; ++i) A[i] = 0.f;

    for (int n = 0; n < 64; ++n) {
        float sd = 0.f;
        #pragma unroll
        for (int i = 0; i < 16; ++i) sd = fmaf(q[i], rlane(kr[i], n), sd);
        const float s = sd * 0.25f + R3[gg * SM + n];
        if (s > m) {
            const float corr = __expf(m - s);
            m = s;
            l = fmaf(l, corr, 1.f);
            #pragma unroll
            for (int i = 0; i < 16; ++i) A[i] = fmaf(A[i], corr, rlane(vr[i], n));
        } else {
            const float p = __expf(s - m);
            l += p;
            #pragma unroll
            for (int i = 0; i < 16; ++i) A[i] = fmaf(p, rlane(vr[i], n), A[i]);
        }
    }
    {
        const int row = min(64 + lane, N_ - 1);   // rows 64..99 in lanes 0..35
        #pragma unroll
        for (int i4 = 0; i4 < 4; ++i4) {
            float4 kk = *(const float4*)&R1[row * SK + c + i4*4];
            float4 vv = *(const float4*)&R2[row * SK + c + i4*4];
            kr[i4*4+0]=kk.x; kr[i4*4+1]=kk.y; kr[i4*4+2]=kk.z; kr[i4*4+3]=kk.w;
            vr[i4*4+0]=vv.x; vr[i4*4+1]=vv.y; vr[i4*4+2]=vv.z; vr[i4*4+3]=vv.w;
        }
    }
    for (int n = 64; n < N_; ++n) {
        const int ln = n - 64;
        float sd = 0.f;
        #pragma unroll
        for (int i = 0; i < 16; ++i) sd = fmaf(q[i], rlane(kr[i], ln), sd);
        const float s = sd * 0.25f + R3[gg * SM + n];
        if (s > m) {
            const float corr = __expf(m - s);
            m = s;
            l = fmaf(l, corr, 1.f);
            #pragma unroll
            for (int i = 0; i < 16; ++i) A[i] = fmaf(A[i], corr, rlane(vr[i], ln));
        } else {
            const float p = __expf(s - m);
            l += p;
            #pragma unroll
            for (int i = 0; i < 16; ++i) A[i] = fmaf(p, rlane(vr[i], ln), A[i]);
        }
    }
    __syncthreads();   // all k/v tile reads done; R2 reusable

    if (g < G_) {
        const float inv = 1.f / l;
        #pragma unroll
        for (int i = 0; i < 16; ++i) R2[g * SO + c + i] = A[i] * inv;   // o
    }
    __syncthreads();

    // ---------------- C0: mh = o @ Wc + bc  -> R1 (stride SO). thread (g,h) ----------------
    {
        float accm[16];
        #pragma unroll
        for (int i = 0; i < 16; ++i) accm[i] = 0.f;
        for (int e = 0; e < E_; ++e) {
            const float ov = R2[gg * SO + e];                 // lane-distinct, conflict-free
            const float4* wr = (const float4*)&Wc[e * E_ + c]; // wave-uniform broadcast
            float4 w0 = wr[0], w1 = wr[1], w2 = wr[2], w3 = wr[3];
            accm[0]  = fmaf(ov, w0.x, accm[0]);  accm[1]  = fmaf(ov, w0.y, accm[1]);
            accm[2]  = fmaf(ov, w0.z, accm[2]);  accm[3]  = fmaf(ov, w0.w, accm[3]);
            accm[4]  = fmaf(ov, w1.x, accm[4]);  accm[5]  = fmaf(ov, w1.y, accm[5]);
            accm[6]  = fmaf(ov, w1.z, accm[6]);  accm[7]  = fmaf(ov, w1.w, accm[7]);
            accm[8]  = fmaf(ov, w2.x, accm[8]);  accm[9]  = fmaf(ov, w2.y, accm[9]);
            accm[10] = fmaf(ov, w2.z, accm[10]); accm[11] = fmaf(ov, w2.w, accm[11]);
            accm[12] = fmaf(ov, w3.x, accm[12]); accm[13] = fmaf(ov, w3.y, accm[13]);
            accm[14] = fmaf(ov, w3.z, accm[14]); accm[15] = fmaf(ov, w3.w, accm[15]);
        }
        if (g < G_) {
            const float4* bv = (const float4*)&bc[c];
            float4 b0 = bv[0], b1 = bv[1], b2 = bv[2], b3 = bv[3];
            R1[g*SO + c + 0]  = accm[0]  + b0.x; R1[g*SO + c + 1]  = accm[1]  + b0.y;
            R1[g*SO + c + 2]  = accm[2]  + b0.z; R1[g*SO + c + 3]  = accm[3]  + b0.w;
            R1[g*SO + c + 4]  = accm[4]  + b1.x; R1[g*SO + c + 5]  = accm[5]  + b1.y;
            R1[g*SO + c + 6]  = accm[6]  + b1.z; R1[g*SO + c + 7]  = accm[7]  + b1.w;
            R1[g*SO + c + 8]  = accm[8]  + b2.x; R1[g*SO + c + 9]  = accm[9]  + b2.y;
            R1[g*SO + c + 10] = accm[10] + b2.z; R1[g*SO + c + 11] = accm[11] + b2.w;
            R1[g*SO + c + 12] = accm[12] + b3.x; R1[g*SO + c + 13] = accm[13] + b3.y;
            R1[g*SO + c + 14] = accm[14] + b3.z; R1[g*SO + c + 15] = accm[15] + b3.w;
        }
    }
    __syncthreads();

    // ---------------- C1: pointer scores + tanh clip + softmax -> R2 (stride SM) ------------
    {
        const int n0 = r8 * 13;
        float acc[13];
        #pragma unroll
        for (int t = 0; t < 13; ++t) acc[t] = 0.f;
        for (int e0 = 0; e0 < E_; e0 += 16) {
            float mh[16];
            #pragma unroll
            for (int i = 0; i < 16; ++i) mh[i] = R1[gg * SO + e0 + i];
            #pragma unroll
            for (int t = 0; t < 13; ++t) {
                const int nn = min(n0 + t, N_ - 1);
                const float4* nr = (const float4*)&nb[nn * E_ + e0];
                float4 x0 = nr[0], x1 = nr[1], x2 = nr[2], x3 = nr[3];
                float a = acc[t];
                a = fmaf(mh[0],  x0.x, a); a = fmaf(mh[1],  x0.y, a);
                a = fmaf(mh[2],  x0.z, a); a = fmaf(mh[3],  x0.w, a);
                a = fmaf(mh[4],  x1.x, a); a = fmaf(mh[5],  x1.y, a);
                a = fmaf(mh[6],  x1.z, a); a = fmaf(mh[7],  x1.w, a);
                a = fmaf(mh[8],  x2.x, a); a = fmaf(mh[9],  x2.y, a);
                a = fmaf(mh[10], x2.z, a); a = fmaf(mh[11], x2.w, a);
                a = fmaf(mh[12], x3.x, a); a = fmaf(mh[13], x3.y, a);
                a = fmaf(mh[14], x3.z, a); a = fmaf(mh[15], x3.w, a);
                acc[t] = a;
            }
        }
        float lpart = 0.f;
        #pragma unroll
        for (int t = 0; t < 13; ++t) {
            const int n = n0 + t;
            if (n < N_ && g < G_) {
                const float sc2 = acc[t] * 0.08838834764831845f;   // 1/sqrt(128)
                const float xc  = fminf(fmaxf(sc2, -15.f), 15.f);
                const float tt  = __expf(2.f * xc);
                const float th  = 1.f - 2.f / (tt + 1.f);
                const float scl = 10.f * th + R3[gg * SM + n];
                const float pe  = __expf(scl - 10.f);              // clipped <= 10
                lpart += pe;
                R2[g * SM + n] = pe;
            }
        }
        RED[tid] = lpart;
    }
    __syncthreads();

    if (g < G_) {
        float tot = 0.f;
        #pragma unroll
        for (int r = 0; r < 8; ++r) tot += RED[r * 128 + g];
        const float inv = 1.f / tot;
        const int n0 = r8 * 13;
        #pragma unroll
        for (int t = 0; t < 13; ++t) {
            const int n = n0 + t;
            if (n < N_) R2[g * SM + n] *= inv;
        }
    }
    __syncthreads();

    for (int idx = tid; idx < G_ * N_; idx += 1024) {
        int gr = idx / N_;
        int nn = idx - gr * N_;
        ob[idx] = R2[gr * SM + nn];
    }
}

extern "C" void kernel_launch(void* const* d_in, const int* in_sizes, int n_in,
                              void* d_out, int out_size, void* d_ws, size_t ws_size,
                              hipStream_t stream) {
    const float* nodes = (const float*)d_in[0];
    const float* last  = (const float*)d_in[1];
    const float* mask  = (const float*)d_in[2];
    const float* Wqg   = (const float*)d_in[3];
    const float* Wqf   = (const float*)d_in[4];
    const float* Wql   = (const float*)d_in[5];
    const float* Wk    = (const float*)d_in[6];
    const float* Wv    = (const float*)d_in[7];
    const float* Wc    = (const float*)d_in[8];
    const float* bc    = (const float*)d_in[9];
    float* out = (float*)d_out;

    const int B = in_sizes[0] / (N_ * E_);   // 2048
    hipLaunchKernelGGL(pomo_decoder, dim3(B), dim3(1024), 0, stream,
                       nodes, last, mask, Wqg, Wqf, Wql, Wk, Wv, Wc, bc, out);
}

// Round 3
// 694.381 us; speedup vs baseline: 4.3664x; 3.9658x over previous
//
#include <hip/hip_runtime.h>
#include <math.h>

#define N_ 100
#define G_ 100
#define E_ 128

typedef short short8 __attribute__((ext_vector_type(8)));
typedef short short4s __attribute__((ext_vector_type(4)));
typedef float f32x4 __attribute__((ext_vector_type(4)));

__device__ __forceinline__ unsigned short f2bf(float x) {
    unsigned u = __float_as_uint(x);
    return (unsigned short)((u + 0x7FFFu + ((u >> 16) & 1u)) >> 16);
}

// ---- prep: bf16 transposed weights into ws ----
// ws layout (bf16): [0]=WsumT(=WqfT+WqlT) [16384]=WkT [32768]=WvT [49152]=WcT
extern "C" __global__ void prep_weights(const float* __restrict__ Wqf,
                                        const float* __restrict__ Wql,
                                        const float* __restrict__ Wk,
                                        const float* __restrict__ Wv,
                                        const float* __restrict__ Wc,
                                        unsigned short* __restrict__ ws) {
    int t = blockIdx.x * 256 + threadIdx.x;      // 0..65535
    int m = t >> 14, r = t & 16383;
    int o = r & 127, i = r >> 7;
    float v;
    if      (m == 0) v = Wqf[i * 128 + o] + Wql[i * 128 + o];
    else if (m == 1) v = Wk [i * 128 + o];
    else if (m == 2) v = Wv [i * 128 + o];
    else             v = Wc [i * 128 + o];
    ws[m * 16384 + o * 128 + i] = f2bf(v);       // W^T[o][i]
}

// LDS element offsets (bf16 elements), total 77440 el = 154880 B
#define OFF_N 0        // nodes  [100][136]
#define OFF_Q 13600    // q -> mh [100][136]
#define OFF_O 27200    // last -> o [100][136]
#define OFF_K 40800    // k half: 4 heads x (16 real + 16 zero) [100][136]
#define OFF_V 54400    // vT half [64][136], cols n>=100 zero
#define OFF_P 63104    // per-wave P: 8 x [16][112]

extern "C" __global__ void __launch_bounds__(512, 2)
pomo_decoder(const float* __restrict__ nodes,   // [B,N,E]
             const float* __restrict__ last,    // [B,G,E]
             const float* __restrict__ mask,    // [B,G,N]
             const float* __restrict__ Wqg,     // [E,128] fp32
             const unsigned short* __restrict__ ws, // bf16 transposed weights
             const float* __restrict__ bc,      // [128]
             float* __restrict__ out)           // [B,G,N]
{
    __shared__ unsigned short SB[77440];
    float* SF = (float*)(SB + OFF_P);           // RED[512], GRAPH[128]@512, QG[128]@640

    const int tid  = threadIdx.x;
    const int w    = tid >> 6;
    const int lane = tid & 63;
    const int lrow = lane & 15;
    const int lq   = lane >> 4;
    const int b    = blockIdx.x;

    const float* nb = nodes + (size_t)b * N_ * E_;
    const float* lb = last  + (size_t)b * G_ * E_;
    const float* mb = mask  + (size_t)b * G_ * N_;
    float*       ob = out   + (size_t)b * G_ * N_;

    const unsigned short* WsumT = ws;
    const unsigned short* WkT   = ws + 16384;
    const unsigned short* WvT   = ws + 32768;
    const unsigned short* WcT   = ws + 49152;

    // ---------- phase 0: stage nodes+last to bf16 LDS, fused mean partials ----------
    {
        float nsum = 0.f;
        const int col = tid & 127;
        #pragma unroll
        for (int it = 0; it < 25; ++it) {
            const int idx = it * 512 + tid;
            const int row = idx >> 7;           // (tid>>7) + 4*it < 100
            float nv = nb[idx];
            nsum += nv;
            SB[OFF_N + row * 136 + col] = f2bf(nv);
            SB[OFF_O + row * 136 + col] = f2bf(lb[idx]);
        }
        SF[tid] = nsum;
    }
    __syncthreads();
    if (tid < 128) {
        float s = SF[tid] + SF[tid + 128] + SF[tid + 256] + SF[tid + 384];
        SF[512 + tid] = s * 0.01f;              // GRAPH
    }
    __syncthreads();
    if (tid < 128) {                            // q_graph = graph @ Wq_graph (fp32)
        float acc = 0.f;
        for (int e = 0; e < 128; ++e) acc = fmaf(SF[512 + e], Wqg[e * 128 + tid], acc);
        SF[640 + tid] = acc;                    // QG
    }
    __syncthreads();

    // ---------- P1: q = last @ Wsum + qg  -> OFF_Q ----------
    for (int i = 0; i < 7; ++i) {
        const int tau = w * 7 + i;              // 0..55
        const int gt = tau >> 3, et = tau & 7;
        f32x4 acc = {0.f, 0.f, 0.f, 0.f};
        #pragma unroll
        for (int kk = 0; kk < 4; ++kk) {
            short8 a = *(const short8*)&SB[OFF_O + (gt * 16 + lrow) * 136 + kk * 32 + lq * 8];
            short8 bb = *(const short8*)(WsumT + (et * 16 + lrow) * 128 + kk * 32 + lq * 8);
            acc = __builtin_amdgcn_mfma_f32_16x16x32_bf16(a, bb, acc, 0, 0, 0);
        }
        const float qg = SF[640 + et * 16 + lrow];
        #pragma unroll
        for (int r = 0; r < 4; ++r) {
            const int g = gt * 16 + lq * 4 + r;
            if (g < G_) SB[OFF_Q + g * 136 + et * 16 + lrow] = f2bf(acc[r] + qg);
        }
    }
    __syncthreads();

    // ---------- zero K, VT, P regions (contiguous [40800,77440)) ----------
    {
        int4 zz = {0, 0, 0, 0};
        int4* zp = (int4*)&SB[OFF_K];           // byte-16 aligned
        for (int i = tid; i < 4580; i += 512) zp[i] = zz;   // 36640 el = 4580 x 16B
    }
    __syncthreads();

    for (int hh = 0; hh < 2; ++hh) {
        // ---------- P2: k,v projections for heads hh*4..hh*4+3 ----------
        for (int i = 0; i < 7; ++i) {
            const int tau = w * 7 + i;          // 0..55: 28 k-tiles then 28 v-tiles
            const bool isK = (tau < 28);
            const int tt = isK ? tau : tau - 28;
            const int nt = tt >> 2, et = tt & 3;
            const int eo = hh * 64 + et * 16 + lrow;
            const unsigned short* WT = isK ? WkT : WvT;
            f32x4 acc = {0.f, 0.f, 0.f, 0.f};
            #pragma unroll
            for (int kk = 0; kk < 4; ++kk) {
                short8 a = *(const short8*)&SB[OFF_N + (nt * 16 + lrow) * 136 + kk * 32 + lq * 8];
                short8 bb = *(const short8*)(WT + eo * 128 + kk * 32 + lq * 8);
                acc = __builtin_amdgcn_mfma_f32_16x16x32_bf16(a, bb, acc, 0, 0, 0);
            }
            if (isK) {
                #pragma unroll
                for (int r = 0; r < 4; ++r) {
                    const int n = nt * 16 + lq * 4 + r;
                    if (n < N_) SB[OFF_K + n * 136 + et * 32 + lrow] = f2bf(acc[r]);
                }
            } else {
                const int e_local = et * 16 + lrow;
                const int n0 = nt * 16 + lq * 4;
                short4s vv;
                #pragma unroll
                for (int r = 0; r < 4; ++r)
                    vv[r] = (short)((n0 + r < N_) ? f2bf(acc[r]) : 0);
                *(short4s*)&SB[OFF_V + e_local * 136 + n0] = vv;   // 8B aligned
            }
        }
        __syncthreads();

        // ---------- P3: attention for 4 heads ----------
        const int base = (w < 4) ? w * 4 : 16 + (w - 4) * 3;
        const int cnt  = (w < 4) ? 4 : 3;
        const int pbase = OFF_P + w * 1792;
        for (int i = 0; i < cnt; ++i) {
            const int tau = base + i;           // 0..27
            const int h_local = tau / 7, gt = tau % 7;
            const int h_global = hh * 4 + h_local;

            short8 qa = *(const short8*)&SB[OFF_Q + (gt * 16 + lrow) * 136 + h_global * 16 + lq * 8];
            f32x4 sc[7];
            #pragma unroll
            for (int nt = 0; nt < 7; ++nt) {
                short8 kb = *(const short8*)&SB[OFF_K + (nt * 16 + lrow) * 136 + h_local * 32 + lq * 8];
                f32x4 z = {0.f, 0.f, 0.f, 0.f};
                sc[nt] = __builtin_amdgcn_mfma_f32_16x16x32_bf16(qa, kb, z, 0, 0, 0);
            }
            // mask + row-max
            const int n_col = lrow;             // tile-local col
            float m4[4] = {-INFINITY, -INFINITY, -INFINITY, -INFINITY};
            #pragma unroll
            for (int nt = 0; nt < 7; ++nt) {
                const int n = nt * 16 + n_col;
                #pragma unroll
                for (int r = 0; r < 4; ++r) {
                    const int g = gt * 16 + lq * 4 + r;
                    float s;
                    if (n < N_) s = sc[nt][r] * 0.25f + mb[min(g, G_ - 1) * N_ + n];
                    else        s = -INFINITY;
                    sc[nt][r] = s;
                    m4[r] = fmaxf(m4[r], s);
                }
            }
            #pragma unroll
            for (int r = 0; r < 4; ++r) {
                #pragma unroll
                for (int off = 1; off < 16; off <<= 1)
                    m4[r] = fmaxf(m4[r], __shfl_xor(m4[r], off));
            }
            float l4[4] = {0.f, 0.f, 0.f, 0.f};
            #pragma unroll
            for (int nt = 0; nt < 7; ++nt) {
                #pragma unroll
                for (int r = 0; r < 4; ++r) {
                    float p = __expf(sc[nt][r] - m4[r]);
                    sc[nt][r] = p;
                    l4[r] += p;
                }
            }
            #pragma unroll
            for (int r = 0; r < 4; ++r) {
                #pragma unroll
                for (int off = 1; off < 16; off <<= 1)
                    l4[r] += __shfl_xor(l4[r], off);
                l4[r] = 1.f / l4[r];
            }
            // write normalized P (bf16) to per-wave buffer
            #pragma unroll
            for (int nt = 0; nt < 7; ++nt) {
                #pragma unroll
                for (int r = 0; r < 4; ++r)
                    SB[pbase + (lq * 4 + r) * 112 + nt * 16 + lrow] = f2bf(sc[nt][r] * l4[r]);
            }
            // O = P @ v
            f32x4 oacc = {0.f, 0.f, 0.f, 0.f};
            #pragma unroll
            for (int kk = 0; kk < 4; ++kk) {
                short8 pa = *(const short8*)&SB[pbase + lrow * 112 + kk * 32 + lq * 8];
                short8 vb = *(const short8*)&SB[OFF_V + (h_local * 16 + lrow) * 136 + kk * 32 + lq * 8];
                oacc = __builtin_amdgcn_mfma_f32_16x16x32_bf16(pa, vb, oacc, 0, 0, 0);
            }
            #pragma unroll
            for (int r = 0; r < 4; ++r) {
                const int g = gt * 16 + lq * 4 + r;
                if (g < G_) SB[OFF_O + g * 136 + h_global * 16 + lrow] = f2bf(oacc[r]);
            }
        }
        __syncthreads();
    }

    // ---------- P4: mh = o @ Wc + bc  -> OFF_Q ----------
    for (int i = 0; i < 7; ++i) {
        const int tau = w * 7 + i;
        const int gt = tau >> 3, et = tau & 7;
        f32x4 acc = {0.f, 0.f, 0.f, 0.f};
        #pragma unroll
        for (int kk = 0; kk < 4; ++kk) {
            short8 a = *(const short8*)&SB[OFF_O + (gt * 16 + lrow) * 136 + kk * 32 + lq * 8];
            short8 bb = *(const short8*)(WcT + (et * 16 + lrow) * 128 + kk * 32 + lq * 8);
            acc = __builtin_amdgcn_mfma_f32_16x16x32_bf16(a, bb, acc, 0, 0, 0);
        }
        const float bcv = bc[et * 16 + lrow];
        #pragma unroll
        for (int r = 0; r < 4; ++r) {
            const int g = gt * 16 + lq * 4 + r;
            if (g < G_) SB[OFF_Q + g * 136 + et * 16 + lrow] = f2bf(acc[r] + bcv);
        }
    }
    __syncthreads();

    // ---------- P5: score2 = mh @ nodes^T, tanh clip, fixed-shift softmax, store ----------
    if (w < 7) {
        const int gt = w;
        short8 af[4];
        #pragma unroll
        for (int kk = 0; kk < 4; ++kk)
            af[kk] = *(const short8*)&SB[OFF_Q + (gt * 16 + lrow) * 136 + kk * 32 + lq * 8];
        f32x4 c[7];
        #pragma unroll
        for (int nt = 0; nt < 7; ++nt) {
            f32x4 acc = {0.f, 0.f, 0.f, 0.f};
            #pragma unroll
            for (int kk = 0; kk < 4; ++kk) {
                short8 bb = *(const short8*)&SB[OFF_N + (nt * 16 + lrow) * 136 + kk * 32 + lq * 8];
                acc = __builtin_amdgcn_mfma_f32_16x16x32_bf16(af[kk], bb, acc, 0, 0, 0);
            }
            c[nt] = acc;
        }
        float l4[4] = {0.f, 0.f, 0.f, 0.f};
        #pragma unroll
        for (int nt = 0; nt < 7; ++nt) {
            const int n = nt * 16 + lrow;
            #pragma unroll
            for (int r = 0; r < 4; ++r) {
                const int g = gt * 16 + lq * 4 + r;
                float p = 0.f;
                if (n < N_) {
                    float x = c[nt][r] * 0.08838834764831845f;     // 1/sqrt(128)
                    x = fminf(fmaxf(x, -15.f), 15.f);
                    const float e2 = __expf(2.f * x);
                    const float th = 1.f - 2.f / (e2 + 1.f);
                    const float scl = 10.f * th + mb[min(g, G_ - 1) * N_ + n];
                    p = __expf(scl - 10.f);                        // clipped <= 10
                }
                c[nt][r] = p;
                l4[r] += p;
            }
        }
        #pragma unroll
        for (int r = 0; r < 4; ++r) {
            #pragma unroll
            for (int off = 1; off < 16; off <<= 1)
                l4[r] += __shfl_xor(l4[r], off);
            l4[r] = 1.f / l4[r];
        }
        #pragma unroll
        for (int nt = 0; nt < 7; ++nt) {
            const int n = nt * 16 + lrow;
            #pragma unroll
            for (int r = 0; r < 4; ++r) {
                const int g = gt * 16 + lq * 4 + r;
                if (g < G_ && n < N_) ob[g * N_ + n] = c[nt][r] * l4[r];
            }
        }
    }
}

extern "C" void kernel_launch(void* const* d_in, const int* in_sizes, int n_in,
                              void* d_out, int out_size, void* d_ws, size_t ws_size,
                              hipStream_t stream) {
    const float* nodes = (const float*)d_in[0];
    const float* last  = (const float*)d_in[1];
    const float* mask  = (const float*)d_in[2];
    const float* Wqg   = (const float*)d_in[3];
    const float* Wqf   = (const float*)d_in[4];
    const float* Wql   = (const float*)d_in[5];
    const float* Wk    = (const float*)d_in[6];
    const float* Wv    = (const float*)d_in[7];
    const float* Wc    = (const float*)d_in[8];
    const float* bc    = (const float*)d_in[9];
    float* out = (float*)d_out;
    unsigned short* ws = (unsigned short*)d_ws;  // needs 131072 B

    hipLaunchKernelGGL(prep_weights, dim3(256), dim3(256), 0, stream,
                       Wqf, Wql, Wk, Wv, Wc, ws);

    const int B = in_sizes[0] / (N_ * E_);       // 2048
    hipLaunchKernelGGL(pomo_decoder, dim3(B), dim3(512), 0, stream,
                       nodes, last, mask, Wqg, ws, bc, out);
}